// Round 14
// baseline (51.626 us; speedup 1.0000x reference)
//
#include <hip/hip_runtime.h>

#define NSTEP 50
#define RND 2             // particle sets per wave, computed sequentially
#define ROWW 75           // LDS dwords per particle row (NO pad: image is linear)
#define NT 64             // one wave per block

__device__ __forceinline__ void lorenz(float x, float y, float z,
                                       float S, float R, float Bb,
                                       float c0, float c1, float c2,
                                       float& dx, float& dy, float& dz) {
    dx = S * (y - x) + c0;
    dy = x * (R - z) - y + c1;
    dz = x * y - Bb * z + c2;
}

// pack two f32 -> two bf16 (round-half-up) in one dword; lo in low half
__device__ __forceinline__ unsigned int bpack(float lo, float hi) {
    unsigned int a = (__builtin_bit_cast(unsigned int, lo) + 0x8000u) >> 16;
    unsigned int b = (__builtin_bit_cast(unsigned int, hi) + 0x8000u) & 0xFFFF0000u;
    return a | b;
}
__device__ __forceinline__ float bunpack_lo(unsigned int w) {
    return __builtin_bit_cast(float, w << 16);
}
__device__ __forceinline__ float bunpack_hi(unsigned int w) {
    return __builtin_bit_cast(float, w & 0xFFFF0000u);
}

__device__ __forceinline__ float tanh_fast(float x) {
    float e = __expf(2.0f * x);
    float r = __builtin_amdgcn_rcpf(e + 1.0f);
    return __builtin_fmaf(-2.0f, r, 1.0f);
}
__device__ __forceinline__ float sigmoid_fast(float x) {
    float e = __expf(-x);
    return __builtin_amdgcn_rcpf(1.0f + e);
}

// LDS-only fence: orders ds ops without draining global stores (which a full
// __syncthreads would do via vmcnt(0) — that would kill the overlap).
__device__ __forceinline__ void lds_fence() {
    asm volatile("s_waitcnt lgkmcnt(0)" ::: "memory");
}

__global__ __launch_bounds__(NT, 2) void chaotic_embed_kernel(
    const float* __restrict__ features,
    const float* __restrict__ W1,  const float* __restrict__ b1,
    const float* __restrict__ W2,  const float* __restrict__ b2,
    const float* __restrict__ Wc1, const float* __restrict__ bc1,
    const float* __restrict__ Wc2, const float* __restrict__ bc2,
    const float* __restrict__ Wp1, const float* __restrict__ bp1,
    const float* __restrict__ Wp2, const float* __restrict__ bp2,
    float* __restrict__ out)
{
    __shared__ unsigned int tile[NT * ROWW];   // 19200 B: LINEAR bf16 image of
                                               // the round's 38400 B out region
    const int lane = threadIdx.x;
    const long pbase = (long)blockIdx.x * (NT * RND);

    // preload both rounds' features
    const float4 f40 = ((const float4*)features)[pbase + lane];
    const float4 f41 = ((const float4*)features)[pbase + NT + lane];

    unsigned int* row = tile + lane * ROWW;    // stride 75 (mod 32 = 11): 2-way only

    for (int r = 0; r < RND; ++r) {
        const float4 f4 = r ? f41 : f40;
        const float fv[4] = {f4.x, f4.y, f4.z, f4.w};

        // ---- MLPs: compile-time weight indices -> uniform s_load, SGPR ops
        float h1[16];
        #pragma unroll
        for (int j = 0; j < 16; ++j) {
            float a = b1[j];
            #pragma unroll
            for (int i = 0; i < 4; ++i) a = __builtin_fmaf(fv[i], W1[i * 16 + j], a);
            h1[j] = tanh_fast(a);
        }
        float init[3];
        #pragma unroll
        for (int c = 0; c < 3; ++c) {
            float a = b2[c];
            #pragma unroll
            for (int j = 0; j < 16; ++j) a = __builtin_fmaf(h1[j], W2[j * 3 + c], a);
            init[c] = 2.0f * tanh_fast(a);
        }
        float hc[8];
        #pragma unroll
        for (int j = 0; j < 8; ++j) {
            float a = bc1[j];
            #pragma unroll
            for (int i = 0; i < 4; ++i) a = __builtin_fmaf(fv[i], Wc1[i * 8 + j], a);
            hc[j] = tanh_fast(a);
        }
        float coup[3];
        #pragma unroll
        for (int c = 0; c < 3; ++c) {
            float a = bc2[c];
            #pragma unroll
            for (int j = 0; j < 8; ++j) a = __builtin_fmaf(hc[j], Wc2[j * 3 + c], a);
            coup[c] = tanh_fast(a);
        }
        float hp[8];
        #pragma unroll
        for (int j = 0; j < 8; ++j) {
            float a = bp1[j];
            #pragma unroll
            for (int i = 0; i < 4; ++i) a = __builtin_fmaf(fv[i], Wp1[i * 8 + j], a);
            hp[j] = fmaxf(a, 0.0f);
        }
        float sc[3];
        #pragma unroll
        for (int c = 0; c < 3; ++c) {
            float a = bp2[c];
            #pragma unroll
            for (int j = 0; j < 8; ++j) a = __builtin_fmaf(hp[j], Wp2[j * 3 + c], a);
            sc[c] = sigmoid_fast(a);
        }
        const float S  = 10.0f * (0.5f + sc[0]);
        const float R  = 28.0f * (0.5f + sc[1]);
        const float Bb = (8.0f / 3.0f) * (0.5f + sc[2]);
        const float c0 = coup[0], c1 = coup[1], c2 = coup[2];
        const float H = 0.01f, HH = 0.5f * 0.01f, H6 = 0.01f / 6.0f;

        float sx = init[0], sy = init[1], sz = init[2];
        float px, py, pz;

        auto step = [&]() {
            float k1x, k1y, k1z, k2x, k2y, k2z, k3x, k3y, k3z, k4x, k4y, k4z;
            lorenz(sx, sy, sz, S, R, Bb, c0, c1, c2, k1x, k1y, k1z);
            lorenz(sx + HH * k1x, sy + HH * k1y, sz + HH * k1z,
                   S, R, Bb, c0, c1, c2, k2x, k2y, k2z);
            lorenz(sx + HH * k2x, sy + HH * k2y, sz + HH * k2z,
                   S, R, Bb, c0, c1, c2, k3x, k3y, k3z);
            lorenz(sx + H * k3x, sy + H * k3y, sz + H * k3z,
                   S, R, Bb, c0, c1, c2, k4x, k4y, k4z);
            sx += H6 * (k1x + 2.0f * k2x + 2.0f * k3x + k4x);
            sy += H6 * (k1y + 2.0f * k2y + 2.0f * k3y + k4y);
            sz += H6 * (k1z + 2.0f * k2z + 2.0f * k3z + k4z);
        };

        // ---- trajectory: 25 entry-pairs -> 75 packed dwords in this lane's row
        {   // pair 0 = (init, step 1)
            px = sx; py = sy; pz = sz;
            step();
            row[0] = bpack(px, py);
            row[1] = bpack(pz, sx);
            row[2] = bpack(sy, sz);
        }
        #pragma unroll 2
        for (int g = 1; g < 25; ++g) {
            step();
            px = sx; py = sy; pz = sz;
            step();
            row[3 * g + 0] = bpack(px, py);
            row[3 * g + 1] = bpack(pz, sx);
            row[3 * g + 2] = bpack(sy, sz);
        }

        lds_fence();   // all lanes' row writes complete (cross-lane visibility)

        // ---- bulk flush: tile is the LINEAR bf16 image of this round's
        // contiguous 38400 B output region (64B-aligned). 2400 float4 stores,
        // every 64B line written exactly once -> zero amplification.
        // No vmcnt wait: stores drain in background under round r+1's compute.
        float4* __restrict__ outv =
            (float4*)out + (long)blockIdx.x * (RND * 2400) + r * 2400;
        const uint2* __restrict__ img2 = (const uint2*)tile;
        #pragma unroll 4
        for (int k = 0; k < 38; ++k) {
            const int i = 64 * k + lane;        // float4 index in [0, 2400)
            if (k < 37 || lane < 32) {
                const uint2 ww = img2[i];       // linear: no div/mod
                float4 v;
                v.x = bunpack_lo(ww.x);
                v.y = bunpack_hi(ww.x);
                v.z = bunpack_lo(ww.y);
                v.w = bunpack_hi(ww.y);
                outv[i] = v;
            }
        }

        lds_fence();   // flush ds_reads complete before next round overwrites
    }
}

extern "C" void kernel_launch(void* const* d_in, const int* in_sizes, int n_in,
                              void* d_out, int out_size, void* d_ws, size_t ws_size,
                              hipStream_t stream) {
    const float* features = (const float*)d_in[0];
    const float* W1  = (const float*)d_in[1];
    const float* b1  = (const float*)d_in[2];
    const float* W2  = (const float*)d_in[3];
    const float* b2  = (const float*)d_in[4];
    const float* Wc1 = (const float*)d_in[5];
    const float* bc1 = (const float*)d_in[6];
    const float* Wc2 = (const float*)d_in[7];
    const float* bc2 = (const float*)d_in[8];
    const float* Wp1 = (const float*)d_in[9];
    const float* bp1 = (const float*)d_in[10];
    const float* Wp2 = (const float*)d_in[11];
    const float* bp2 = (const float*)d_in[12];
    float* out = (float*)d_out;

    const int B = in_sizes[0] / 4;          // 262144
    const int grid = B / (NT * RND);        // 2048 blocks, 8/CU, all resident

    chaotic_embed_kernel<<<grid, NT, 0, stream>>>(
        features, W1, b1, W2, b2, Wc1, bc1, Wc2, bc2,
        Wp1, bp1, Wp2, bp2, out);
}